// Round 6
// baseline (541.559 us; speedup 1.0000x reference)
//
#include <hip/hip_runtime.h>
#include <stdint.h>

typedef unsigned short u16;
typedef short bf16x8 __attribute__((ext_vector_type(8)));
typedef float f32x4 __attribute__((ext_vector_type(4)));
typedef u16 u16x4 __attribute__((ext_vector_type(4)));
typedef u16 u16x8 __attribute__((ext_vector_type(8)));

#define LOG2E 1.4426950408889634f

__device__ __forceinline__ u16 f2bf(float f) {
  union { float f; uint32_t u; } x; x.f = f;
  uint32_t r = x.u + 0x7fffu + ((x.u >> 16) & 1u);
  return (u16)(r >> 16);
}
// round-half-up bf16 pack (2 VALU ops); fine for finite values
__device__ __forceinline__ u16 f2bf_ru(float f) {
  union { float f; uint32_t u; } x; x.f = f;
  return (u16)((x.u + 0x8000u) >> 16);
}
__device__ __forceinline__ float bf2f(u16 h) {
  union { uint32_t u; float f; } x; x.u = ((uint32_t)h) << 16;
  return x.f;
}
// pack 2 f32 -> 2 bf16 in one u32 (lo in low half)
__device__ __forceinline__ uint32_t cvtpk(float lo, float hi) {
  uint32_t r;
  asm("v_cvt_pk_bf16_f32 %0, %1, %2" : "=v"(r) : "v"(lo), "v"(hi));
  return r;
}
// 16B-granule XOR swizzle (involution within 8 granules)
__device__ __forceinline__ int swz3(int row) { return (row ^ (row >> 3)) & 7; }

__device__ __forceinline__ void gload_lds16(const void* g, void* lds) {
  __builtin_amdgcn_global_load_lds(
      (const __attribute__((address_space(1))) void*)g,
      (__attribute__((address_space(3))) void*)lds, 16, 0, 0);
}

// ---------------- cast f32 -> bf16 (8 elems/thread) ----------------
__global__ __launch_bounds__(256) void cast_bf16(const float* __restrict__ in,
                                                 u16* __restrict__ out, int n8) {
  int i = blockIdx.x * 256 + threadIdx.x;
  const int stride = gridDim.x * 256;
  for (; i < n8; i += stride) {
    const f32x4* p = (const f32x4*)in + (size_t)i * 2;
    f32x4 a = p[0], b = p[1];
    u16x8 o;
    o[0] = f2bf(a[0]); o[1] = f2bf(a[1]); o[2] = f2bf(a[2]); o[3] = f2bf(a[3]);
    o[4] = f2bf(b[0]); o[5] = f2bf(b[1]); o[6] = f2bf(b[2]); o[7] = f2bf(b[3]);
    ((u16x8*)out)[i] = o;
  }
}

// ---------------- concat 3 bias vectors (1024 each) ----------------
__global__ __launch_bounds__(256) void concat3(const float* __restrict__ a,
                                               const float* __restrict__ b,
                                               const float* __restrict__ c,
                                               float* __restrict__ o) {
  int i = blockIdx.x * 256 + threadIdx.x;
  if (i < 3072) o[i] = i < 1024 ? a[i] : (i < 2048 ? b[i - 1024] : c[i - 2048]);
}

// ---------------- transpose + cast: W[R][C] f32 -> WT[C][R] bf16 ----------------
__global__ __launch_bounds__(256) void transpose_cast(const float* __restrict__ in,
                                                      u16* __restrict__ out, int R, int C) {
  __shared__ float tile[32][33];
  const int bc = blockIdx.x * 32, br = blockIdx.y * 32;
  const int tx = threadIdx.x & 31, ty = threadIdx.x >> 5;  // 32 x 8
#pragma unroll
  for (int i = 0; i < 32; i += 8)
    tile[ty + i][tx] = in[(size_t)(br + ty + i) * C + bc + tx];
  __syncthreads();
#pragma unroll
  for (int i = 0; i < 32; i += 8)
    out[(size_t)(bc + ty + i) * R + br + tx] = f2bf(tile[tx][ty + i]);
}

// ---------------- GEMM, 3-slot ring + counted vmcnt ----------------
// C[M][N] = A[M][K] @ BT[N][K]^T + bias. BM=256, BN=128, BK=64.
// 512 thr = 8 waves (4M x 2N), per-wave 64x64 out, 32 MFMA/K-tile.
// While computing tile t from slot t%3, stage tile t+2 into (t+2)%3;
// at tile end: s_waitcnt vmcnt(6) (tile t+1 landed, t+2 in flight) + s_barrier.
template <int RELU>
__global__ __launch_bounds__(512, 2) void gemm3r(const u16* __restrict__ A,
                                                 const u16* __restrict__ BT,
                                                 const float* __restrict__ bias,
                                                 u16* __restrict__ Cb,
                                                 int M, int N, int K, int nbx) {
  __shared__ u16 As[3][256 * 64];  // 96 KB
  __shared__ u16 Bs[3][128 * 64];  // 48 KB
  const int t = threadIdx.x;
  const int w = t >> 6, lane = t & 63;
  const int la = lane & 15, lb = lane >> 4;
  const int wr = w >> 1, wc = w & 1;
  // XCD-aware swizzle (grid % 8 == 0 for all our shapes)
  int bid = (int)blockIdx.x;
  const int cpx = (int)gridDim.x >> 3;
  bid = (bid & 7) * cpx + (bid >> 3);
  const int m0 = (bid / nbx) * 256, n0 = (bid % nbx) * 128;
  const int NT = K >> 6;

#define STAGE_G(tile, slot)                                                          \
  {                                                                                  \
    const int kt_ = (tile) << 6;                                                     \
    _Pragma("unroll") for (int i = 0; i < 4; i++) {                                  \
      const int s = i * 512 + t;                                                     \
      const int row = s >> 3;                                                        \
      const int colp = ((s & 7) ^ swz3(row)) << 3;                                   \
      gload_lds16(A + (size_t)(m0 + row) * K + kt_ + colp,                           \
                  &As[slot][(i * 512 + w * 64) * 8]);                                \
    }                                                                                \
    _Pragma("unroll") for (int i = 0; i < 2; i++) {                                  \
      const int s = i * 512 + t;                                                     \
      const int row = s >> 3;                                                        \
      const int colp = ((s & 7) ^ swz3(row)) << 3;                                   \
      gload_lds16(BT + (size_t)(n0 + row) * K + kt_ + colp,                          \
                  &Bs[slot][(i * 512 + w * 64) * 8]);                                \
    }                                                                                \
  }

  f32x4 acc[4][4];
#pragma unroll
  for (int i = 0; i < 4; i++)
#pragma unroll
    for (int j = 0; j < 4; j++) acc[i][j] = (f32x4){0.f, 0.f, 0.f, 0.f};

  STAGE_G(0, 0);
  STAGE_G(1, 1);
  asm volatile("s_waitcnt vmcnt(6)" ::: "memory");  // tile0 landed
  __builtin_amdgcn_s_barrier();
  __builtin_amdgcn_sched_barrier(0);

  int slot = 0;
  for (int tile = 0; tile < NT; ++tile) {
    if (tile + 2 < NT) {
      const int s2 = slot >= 1 ? slot - 1 : 2;  // (slot+2)%3
      STAGE_G(tile + 2, s2);
    }
    bf16x8 af[4][2], bfr[4][2];
#pragma unroll
    for (int m = 0; m < 4; m++)
#pragma unroll
      for (int ks = 0; ks < 2; ks++) {
        const int r = wr * 64 + m * 16 + la;
        af[m][ks] = *(const bf16x8*)&As[slot][r * 64 + ((((ks << 2) + lb) ^ swz3(r)) << 3)];
      }
#pragma unroll
    for (int n = 0; n < 4; n++)
#pragma unroll
      for (int ks = 0; ks < 2; ks++) {
        const int r = wc * 64 + n * 16 + la;
        bfr[n][ks] = *(const bf16x8*)&Bs[slot][r * 64 + ((((ks << 2) + lb) ^ swz3(r)) << 3)];
      }
    __builtin_amdgcn_s_setprio(1);
#pragma unroll
    for (int ks = 0; ks < 2; ks++)
#pragma unroll
      for (int m = 0; m < 4; m++)
#pragma unroll
        for (int n = 0; n < 4; n++)
          acc[m][n] = __builtin_amdgcn_mfma_f32_16x16x32_bf16(af[m][ks], bfr[n][ks], acc[m][n], 0, 0, 0);
    __builtin_amdgcn_s_setprio(0);
    if (tile + 2 < NT) {
      asm volatile("s_waitcnt vmcnt(6)" ::: "memory");  // tile t+1 landed
    } else {
      asm volatile("s_waitcnt vmcnt(0)" ::: "memory");  // tail: drain
    }
    __builtin_amdgcn_s_barrier();
    __builtin_amdgcn_sched_barrier(0);
    slot = (slot == 2) ? 0 : slot + 1;
  }
#undef STAGE_G

  // epilogue: row = m0+wr*64+m*16+lb*4+rr, col = n0+wc*64+n*16+la
#pragma unroll
  for (int m = 0; m < 4; m++) {
    const int r = m0 + wr * 64 + m * 16 + lb * 4;
#pragma unroll
    for (int n = 0; n < 4; n++) {
      const int c = n0 + wc * 64 + n * 16 + la;
      const float bv = bias[c];
#pragma unroll
      for (int rr = 0; rr < 4; rr++) {
        float v = acc[m][n][rr] + bv;
        if (RELU) v = fmaxf(v, 0.f);
        Cb[(size_t)(r + rr) * N + c] = f2bf(v);
      }
    }
  }
}

// ---------------- flash attention fwd (swapped QK^T, in-register P) ----------------
// grid: (S/128, H, B); 4 waves, each owns 32 q-rows. KVBLK=64. D_HEAD=64.
__global__ __launch_bounds__(256) void attn_fwd(const u16* __restrict__ Qg,
                                                const u16* __restrict__ Kg,
                                                const u16* __restrict__ Vg,
                                                u16* __restrict__ Og, int LDM) {
  constexpr int S = 2048, DH = 64, KB = 64, DMO = 1024;
  __shared__ u16 Ks[KB * DH];  // [kv][dh], 16B-granule swizzled
  __shared__ u16 Vt[DH * KB];  // [dh][kv], swizzled
  const int t = threadIdx.x, w = t >> 6, lane = t & 63;
  const int la = lane & 15, lb = lane >> 4;
  const int qb = blockIdx.x, h = blockIdx.y, b = blockIdx.z;
  const size_t base = ((size_t)b * S) * LDM + h * DH;
  const size_t obase = ((size_t)b * S) * DMO + h * DH;
  const int qrow0 = qb * 128 + w * 32;
  const int s0 = la + 32 * (lb & 1);
  const int s1 = s0 + 16;
  const int jsel = lb >> 1;

  bf16x8 qf[2][2];
#pragma unroll
  for (int rf = 0; rf < 2; rf++)
#pragma unroll
    for (int ks = 0; ks < 2; ks++)
      qf[rf][ks] = *(const bf16x8*)&Qg[base + (size_t)(qrow0 + rf * 16 + la) * LDM + ks * 32 + lb * 8];

  f32x4 accO[2][4];
  float m[2], l[2];
#pragma unroll
  for (int i = 0; i < 2; i++) {
    m[i] = -1e30f; l[i] = 0.f;
#pragma unroll
    for (int j = 0; j < 4; j++) accO[i][j] = (f32x4){0.f, 0.f, 0.f, 0.f};
  }

  const float SC = 0.125f * LOG2E;

  for (int kt = 0; kt < S; kt += KB) {
    __syncthreads();
#pragma unroll
    for (int i = 0; i < 2; i++) {
      const int s = i * 256 + t;
      const int row = s >> 3;
      const int colp = ((s & 7) ^ swz3(row)) << 3;
      gload_lds16(Kg + base + (size_t)(kt + row) * LDM + colp, &Ks[(i * 256 + w * 64) * 8]);
    }
#pragma unroll
    for (int i = 0; i < 2; i++) {
      const int s = i * 256 + t;
      const int row = s >> 3, col = (s & 7) * 8;
      bf16x8 vv = *(const bf16x8*)&Vg[base + (size_t)(kt + row) * LDM + col];
#pragma unroll
      for (int e = 0; e < 8; e++) {
        const int dr = col + e;
        Vt[dr * KB + (row ^ (swz3(dr) << 3))] = (u16)vv[e];
      }
    }
    __syncthreads();

    // S^T = K @ Q^T : lane holds q=la, kv=16j+4lb+rr
    f32x4 st[4][2];
#pragma unroll
    for (int j = 0; j < 4; j++)
#pragma unroll
      for (int rf = 0; rf < 2; rf++) st[j][rf] = (f32x4){0.f, 0.f, 0.f, 0.f};
    __builtin_amdgcn_s_setprio(1);
#pragma unroll
    for (int ks = 0; ks < 2; ks++) {
      bf16x8 kf[4];
#pragma unroll
      for (int j = 0; j < 4; j++) {
        const int r = j * 16 + la;
        kf[j] = *(const bf16x8*)&Ks[r * DH + ((((ks << 2) + lb) ^ swz3(r)) << 3)];
      }
#pragma unroll
      for (int j = 0; j < 4; j++)
#pragma unroll
        for (int rf = 0; rf < 2; rf++)
          st[j][rf] = __builtin_amdgcn_mfma_f32_16x16x32_bf16(kf[j], qf[rf][ks], st[j][rf], 0, 0, 0);
    }
    __builtin_amdgcn_s_setprio(0);

    bf16x8 pf[2][2];
#pragma unroll
    for (int rf = 0; rf < 2; rf++) {
      float rm = st[0][rf][0];
#pragma unroll
      for (int j = 0; j < 4; j++)
#pragma unroll
        for (int rr = 0; rr < 4; rr++) rm = fmaxf(rm, st[j][rf][rr]);
      rm *= SC;
      if (__any(rm > m[rf])) {
        rm = fmaxf(rm, __shfl_xor(rm, 16, 64));
        rm = fmaxf(rm, __shfl_xor(rm, 32, 64));
        const float mN = fmaxf(m[rf], rm);
        const float al = exp2f(m[rf] - mN);
        m[rf] = mN;
        l[rf] *= al;
#pragma unroll
        for (int rr = 0; rr < 4; rr++) {
          const float alr = __shfl(al, (lb << 2) + rr, 64);
#pragma unroll
          for (int cf = 0; cf < 4; cf++) accO[rf][cf][rr] *= alr;
        }
      }
      uint32_t wl[4], wh[4];
#pragma unroll
      for (int j = 0; j < 4; j++) {
        float p0 = exp2f(st[j][rf][0] * SC - m[rf]);
        float p1 = exp2f(st[j][rf][1] * SC - m[rf]);
        float p2 = exp2f(st[j][rf][2] * SC - m[rf]);
        float p3 = exp2f(st[j][rf][3] * SC - m[rf]);
        l[rf] += (p0 + p1) + (p2 + p3);
        wl[j] = cvtpk(p0, p1);
        wh[j] = cvtpk(p2, p3);
      }
#pragma unroll
      for (int ks = 0; ks < 2; ks++) {
        const int j0 = 2 * ks, j1 = 2 * ks + 1;
        uint32_t a0 = __shfl(wl[j0], s0, 64), a1 = __shfl(wh[j0], s0, 64);
        uint32_t a2 = __shfl(wl[j0], s1, 64), a3 = __shfl(wh[j0], s1, 64);
        uint32_t b0 = __shfl(wl[j1], s0, 64), b1 = __shfl(wh[j1], s0, 64);
        uint32_t b2 = __shfl(wl[j1], s1, 64), b3 = __shfl(wh[j1], s1, 64);
        union { uint32_t u[4]; bf16x8 v; } pk;
        pk.u[0] = jsel ? b0 : a0;
        pk.u[1] = jsel ? b1 : a1;
        pk.u[2] = jsel ? b2 : a2;
        pk.u[3] = jsel ? b3 : a3;
        pf[rf][ks] = pk.v;
      }
    }

    __builtin_amdgcn_s_setprio(1);
#pragma unroll
    for (int ks = 0; ks < 2; ks++) {
      bf16x8 vf[4];
#pragma unroll
      for (int cf = 0; cf < 4; cf++) {
        const int dr = cf * 16 + la;
        vf[cf] = *(const bf16x8*)&Vt[dr * KB + ((((ks << 2) + lb) ^ swz3(dr)) << 3)];
      }
#pragma unroll
      for (int rf = 0; rf < 2; rf++)
#pragma unroll
        for (int cf = 0; cf < 4; cf++)
          accO[rf][cf] = __builtin_amdgcn_mfma_f32_16x16x32_bf16(pf[rf][ks], vf[cf], accO[rf][cf], 0, 0, 0);
    }
    __builtin_amdgcn_s_setprio(0);
  }

#pragma unroll
  for (int rf = 0; rf < 2; rf++) {
    float l2 = l[rf];
    l2 += __shfl_xor(l2, 16, 64);
    l2 += __shfl_xor(l2, 32, 64);
    const float inv = 1.0f / l2;
#pragma unroll
    for (int rr = 0; rr < 4; rr++) {
      const float invr = __shfl(inv, (lb << 2) + rr, 64);
      const int r = qrow0 + rf * 16 + lb * 4 + rr;
#pragma unroll
      for (int cf = 0; cf < 4; cf++)
        Og[obase + (size_t)r * DMO + cf * 16 + la] = f2bf_ru(accO[rf][cf][rr] * invr);
    }
  }
}

// ---------------- fused residual-add + LayerNorm (D=1024) ----------------
template <int AF32, int OUTF32>
__global__ __launch_bounds__(256) void add_ln(const void* __restrict__ Ap,
                                              const u16* __restrict__ Bb,
                                              const float* __restrict__ g,
                                              const float* __restrict__ be,
                                              void* __restrict__ Yp) {
  constexpr int D = 1024;
  const int row = blockIdx.x, t = threadIdx.x;
  f32x4 a;
  if (AF32) {
    a = ((const f32x4*)((const float*)Ap + (size_t)row * D))[t];
  } else {
    u16x4 av = ((const u16x4*)((const u16*)Ap + (size_t)row * D))[t];
#pragma unroll
    for (int i = 0; i < 4; i++) a[i] = bf2f(av[i]);
  }
  u16x4 bv16 = ((const u16x4*)(Bb + (size_t)row * D))[t];
  f32x4 x;
#pragma unroll
  for (int i = 0; i < 4; i++) x[i] = a[i] + bf2f(bv16[i]);
  float s1 = x[0] + x[1] + x[2] + x[3];
  float s2 = x[0] * x[0] + x[1] * x[1] + x[2] * x[2] + x[3] * x[3];
#pragma unroll
  for (int off = 32; off > 0; off >>= 1) {
    s1 += __shfl_down(s1, off, 64);
    s2 += __shfl_down(s2, off, 64);
  }
  __shared__ float sm[8];
  const int w = t >> 6, lane = t & 63;
  if (lane == 0) { sm[w] = s1; sm[4 + w] = s2; }
  __syncthreads();
  s1 = sm[0] + sm[1] + sm[2] + sm[3];
  s2 = sm[4] + sm[5] + sm[6] + sm[7];
  const float mean = s1 * (1.0f / D);
  const float var = s2 * (1.0f / D) - mean * mean;
  const float rstd = rsqrtf(var + 1e-5f);
  const f32x4 gv = ((const f32x4*)g)[t];
  const f32x4 bv = ((const f32x4*)be)[t];
  f32x4 y;
#pragma unroll
  for (int i = 0; i < 4; i++) y[i] = (x[i] - mean) * rstd * gv[i] + bv[i];
  if (OUTF32) {
    ((f32x4*)((float*)Yp + (size_t)row * D))[t] = y;
  } else {
    u16x4 o;
#pragma unroll
    for (int i = 0; i < 4; i++) o[i] = f2bf(y[i]);
    ((u16x4*)((u16*)Yp + (size_t)row * D))[t] = o;
  }
}

extern "C" void kernel_launch(void* const* d_in, const int* in_sizes, int n_in,
                              void* d_out, int out_size, void* d_ws, size_t ws_size,
                              hipStream_t stream) {
  const float* X   = (const float*)d_in[0];
  const float* Wq  = (const float*)d_in[1];
  const float* bq  = (const float*)d_in[2];
  const float* Wk  = (const float*)d_in[3];
  const float* bk  = (const float*)d_in[4];
  const float* Wv  = (const float*)d_in[5];
  const float* bv  = (const float*)d_in[6];
  const float* Wo  = (const float*)d_in[7];
  const float* bo  = (const float*)d_in[8];
  const float* g1  = (const float*)d_in[9];
  const float* be1 = (const float*)d_in[10];
  const float* W1  = (const float*)d_in[11];
  const float* b1  = (const float*)d_in[12];
  const float* W2  = (const float*)d_in[13];
  const float* b2  = (const float*)d_in[14];
  const float* g2  = (const float*)d_in[15];
  const float* be2 = (const float*)d_in[16];

  // ---- workspace plan (peak 120 MB, lifetime-aliased) ----
  const size_t MB = 1ull << 20;
  char* wsb = (char*)d_ws;
  u16*   WqkvT = (u16*)(wsb + 0 * MB);
  u16*   WoT   = (u16*)(wsb + 6 * MB);
  u16*   W1T   = (u16*)(wsb + 8 * MB);
  u16*   W2T   = (u16*)(wsb + 16 * MB);
  u16*   Xb    = (u16*)(wsb + 24 * MB);
  u16*   Ab    = (u16*)(wsb + 24 * MB);
  u16*   Fb    = (u16*)(wsb + 24 * MB);
  u16*   QKVb  = (u16*)(wsb + 40 * MB);
  u16*   Hb    = (u16*)(wsb + 40 * MB);
  float* bqkv  = (float*)(wsb + 88 * MB);
  u16*   Cx    = (u16*)(wsb + 88 * MB);
  u16*   Yb    = (u16*)(wsb + 104 * MB);
  (void)ws_size; (void)in_sizes; (void)n_in; (void)out_size;

  cast_bf16<<<2048, 256, 0, stream>>>(X, Xb, 8192 * 1024 / 8);
  concat3<<<12, 256, 0, stream>>>(bq, bk, bv, bqkv);
  transpose_cast<<<dim3(32, 32), 256, 0, stream>>>(Wq, WqkvT, 1024, 1024);
  transpose_cast<<<dim3(32, 32), 256, 0, stream>>>(Wk, WqkvT + 1024 * 1024, 1024, 1024);
  transpose_cast<<<dim3(32, 32), 256, 0, stream>>>(Wv, WqkvT + 2 * 1024 * 1024, 1024, 1024);
  transpose_cast<<<dim3(32, 32), 256, 0, stream>>>(Wo, WoT, 1024, 1024);
  transpose_cast<<<dim3(128, 32), 256, 0, stream>>>(W1, W1T, 1024, 4096);
  transpose_cast<<<dim3(32, 128), 256, 0, stream>>>(W2, W2T, 4096, 1024);

  // fused QKV projection: [8192,1024] @ [1024,3072] -> [8192,3072]
  gemm3r<0><<<32 * 24, 512, 0, stream>>>(Xb, WqkvT, bqkv, QKVb, 8192, 3072, 1024, 24);

  attn_fwd<<<dim3(16, 16, 4), 256, 0, stream>>>(QKVb, QKVb + 1024, QKVb + 2048, Cx, 3072);

  gemm3r<0><<<32 * 8, 512, 0, stream>>>(Cx, WoT, bo, Ab, 8192, 1024, 1024, 8);
  add_ln<1, 0><<<8192, 256, 0, stream>>>(X, Ab, g1, be1, Yb);
  gemm3r<1><<<32 * 32, 512, 0, stream>>>(Yb, W1T, b1, Hb, 8192, 4096, 1024, 32);
  gemm3r<0><<<32 * 8, 512, 0, stream>>>(Hb, W2T, b2, Fb, 8192, 1024, 4096, 8);
  add_ln<0, 1><<<8192, 256, 0, stream>>>(Yb, Fb, g2, be2, d_out);
}

// Round 7
// 519.939 us; speedup vs baseline: 1.0416x; 1.0416x over previous
//
#include <hip/hip_runtime.h>
#include <stdint.h>

typedef unsigned short u16;
typedef short bf16x8 __attribute__((ext_vector_type(8)));
typedef float f32x4 __attribute__((ext_vector_type(4)));
typedef u16 u16x4 __attribute__((ext_vector_type(4)));
typedef u16 u16x8 __attribute__((ext_vector_type(8)));

#define LOG2E 1.4426950408889634f

__device__ __forceinline__ u16 f2bf(float f) {
  union { float f; uint32_t u; } x; x.f = f;
  uint32_t r = x.u + 0x7fffu + ((x.u >> 16) & 1u);
  return (u16)(r >> 16);
}
__device__ __forceinline__ u16 f2bf_ru(float f) {
  union { float f; uint32_t u; } x; x.f = f;
  return (u16)((x.u + 0x8000u) >> 16);
}
__device__ __forceinline__ float bf2f(u16 h) {
  union { uint32_t u; float f; } x; x.u = ((uint32_t)h) << 16;
  return x.f;
}
__device__ __forceinline__ uint32_t cvtpk(float lo, float hi) {
  uint32_t r;
  asm("v_cvt_pk_bf16_f32 %0, %1, %2" : "=v"(r) : "v"(lo), "v"(hi));
  return r;
}
// 16B-granule XOR swizzle (involution; depends only on row mod 64)
__device__ __forceinline__ int swz3(int row) { return (row ^ (row >> 3)) & 7; }

__device__ __forceinline__ void gload_lds16(const void* g, void* lds) {
  __builtin_amdgcn_global_load_lds(
      (const __attribute__((address_space(1))) void*)g,
      (__attribute__((address_space(3))) void*)lds, 16, 0, 0);
}

// ---------------- cast f32 -> bf16 (8 elems/thread) ----------------
__global__ __launch_bounds__(256) void cast_bf16(const float* __restrict__ in,
                                                 u16* __restrict__ out, int n8) {
  int i = blockIdx.x * 256 + threadIdx.x;
  const int stride = gridDim.x * 256;
  for (; i < n8; i += stride) {
    const f32x4* p = (const f32x4*)in + (size_t)i * 2;
    f32x4 a = p[0], b = p[1];
    u16x8 o;
    o[0] = f2bf(a[0]); o[1] = f2bf(a[1]); o[2] = f2bf(a[2]); o[3] = f2bf(a[3]);
    o[4] = f2bf(b[0]); o[5] = f2bf(b[1]); o[6] = f2bf(b[2]); o[7] = f2bf(b[3]);
    ((u16x8*)out)[i] = o;
  }
}

// ---------------- concat 3 bias vectors (1024 each) ----------------
__global__ __launch_bounds__(256) void concat3(const float* __restrict__ a,
                                               const float* __restrict__ b,
                                               const float* __restrict__ c,
                                               float* __restrict__ o) {
  int i = blockIdx.x * 256 + threadIdx.x;
  if (i < 3072) o[i] = i < 1024 ? a[i] : (i < 2048 ? b[i - 1024] : c[i - 2048]);
}

// ---------------- transpose + cast: W[R][C] f32 -> WT[C][R] bf16 ----------------
__global__ __launch_bounds__(256) void transpose_cast(const float* __restrict__ in,
                                                      u16* __restrict__ out, int R, int C) {
  __shared__ float tile[32][33];
  const int bc = blockIdx.x * 32, br = blockIdx.y * 32;
  const int tx = threadIdx.x & 31, ty = threadIdx.x >> 5;  // 32 x 8
#pragma unroll
  for (int i = 0; i < 32; i += 8)
    tile[ty + i][tx] = in[(size_t)(br + ty + i) * C + bc + tx];
  __syncthreads();
#pragma unroll
  for (int i = 0; i < 32; i += 8)
    out[(size_t)(bc + ty + i) * R + br + tx] = f2bf(tile[tx][ty + i]);
}

// ---------------- GEMM m97-structure (kept for N=1024 shapes) ----------------
template <int RELU>
__global__ __launch_bounds__(256) void gemm_bt(const u16* __restrict__ A,
                                               const u16* __restrict__ BT,
                                               const float* __restrict__ bias,
                                               u16* __restrict__ Cb,
                                               int M, int N, int K) {
  constexpr int BM = 128, BN = 128, BK = 64;
  __shared__ u16 As[BM * BK];
  __shared__ u16 Bs[BN * BK];
  const int t = threadIdx.x;
  const int w = t >> 6, lane = t & 63;
  const int la = lane & 15, lb = lane >> 4;
  const int wr = w >> 1, wc = w & 1;
  const int m0 = blockIdx.y * BM, n0 = blockIdx.x * BN;

  f32x4 acc[4][4];
#pragma unroll
  for (int i = 0; i < 4; i++)
#pragma unroll
    for (int j = 0; j < 4; j++) acc[i][j] = (f32x4){0.f, 0.f, 0.f, 0.f};

  for (int kt = 0; kt < K; kt += BK) {
#pragma unroll
    for (int i = 0; i < 4; i++) {
      const int s = i * 256 + t;
      const int row = s >> 3, col = (s & 7) * 8;
      gload_lds16(A + (size_t)(m0 + row) * K + kt + col, &As[(i * 256 + w * 64) * 8]);
      gload_lds16(BT + (size_t)(n0 + row) * K + kt + col, &Bs[(i * 256 + w * 64) * 8]);
    }
    __syncthreads();
#pragma unroll
    for (int ks = 0; ks < 2; ks++) {
      bf16x8 af[4], bfr[4];
#pragma unroll
      for (int i = 0; i < 4; i++)
        af[i] = *(const bf16x8*)&As[(wr * 64 + i * 16 + la) * BK + ks * 32 + lb * 8];
#pragma unroll
      for (int j = 0; j < 4; j++)
        bfr[j] = *(const bf16x8*)&Bs[(wc * 64 + j * 16 + la) * BK + ks * 32 + lb * 8];
#pragma unroll
      for (int i = 0; i < 4; i++)
#pragma unroll
        for (int j = 0; j < 4; j++)
          acc[i][j] = __builtin_amdgcn_mfma_f32_16x16x32_bf16(af[i], bfr[j], acc[i][j], 0, 0, 0);
    }
    __syncthreads();
  }
#pragma unroll
  for (int i = 0; i < 4; i++) {
    const int r = m0 + wr * 64 + i * 16 + lb * 4;
#pragma unroll
    for (int j = 0; j < 4; j++) {
      const int c = n0 + wc * 64 + j * 16 + la;
      const float bv = bias[c];
#pragma unroll
      for (int rr = 0; rr < 4; rr++) {
        float v = acc[i][j][rr] + bv;
        if (RELU) v = fmaxf(v, 0.f);
        Cb[(size_t)(r + rr) * N + c] = f2bf(v);
      }
    }
  }
}

// ---------------- GEMM 256x256, 4-phase interleave + counted vmcnt ----------------
// 8 waves (2M x 4N), per-wave 128x64 (8x4 frags), BK=64, dbuf LDS 128KB.
// Per phase: ds_read frags || stage 2 quarters of next K-tile || 16 MFMA.
// Counted waits: vmcnt(4) end-ph1 (protects A-q1/q3), vmcnt(2) end-ph3
// (protects next ph0's A-q0/q2 + all B). Queue math verified by simulation.
template <int RELU>
__global__ __launch_bounds__(512, 2) void gemm8p(const u16* __restrict__ A,
                                                 const u16* __restrict__ BT,
                                                 const float* __restrict__ bias,
                                                 u16* __restrict__ Cb,
                                                 int M, int N, int K, int nbx) {
  __shared__ u16 As[2][256 * 64];  // 64 KB
  __shared__ u16 Bs[2][256 * 64];  // 64 KB
  const int t = threadIdx.x;
  const int w = t >> 6, lane = t & 63;
  const int la = lane & 15, lb = lane >> 4;
  const int wr = w >> 2, wc = w & 3;  // 2M x 4N
  int bid = (int)blockIdx.x;
  const int cpx = (int)gridDim.x >> 3;
  bid = (bid & 7) * cpx + (bid >> 3);  // XCD swizzle (grid % 8 == 0)
  const int m0 = (bid / nbx) * 256, n0 = (bid % nbx) * 256;
  const int NT = K >> 6;
  // staging coords: each thread loads one 16B granule per chunk
  const int row64 = t >> 3;                      // 0..63 within a quarter
  const int colp = ((t & 7) ^ swz3(row64)) << 3; // pre-swizzled source col

#define STG_A(buf, tile, q) \
  gload_lds16(A + (size_t)(m0 + (q)*64 + row64) * K + ((tile) << 6) + colp, \
              &As[buf][(q)*4096 + w * 512])
#define STG_B(buf, tile, q) \
  gload_lds16(BT + (size_t)(n0 + (q)*64 + row64) * K + ((tile) << 6) + colp, \
              &Bs[buf][(q)*4096 + w * 512])
#define LDA(dst, mf, ks) { const int r_ = wr * 128 + (mf)*16 + la; \
  dst = *(const bf16x8*)&As[cur][r_ * 64 + (((((ks) << 2) + lb) ^ swz3(r_)) << 3)]; }
#define LDB(dst, nf, ks) { const int r_ = wc * 64 + (nf)*16 + la; \
  dst = *(const bf16x8*)&Bs[cur][r_ * 64 + (((((ks) << 2) + lb) ^ swz3(r_)) << 3)]; }
#define MFMA16(mh, nh) \
  __builtin_amdgcn_s_setprio(1); \
  _Pragma("unroll") for (int ks = 0; ks < 2; ks++) \
  _Pragma("unroll") for (int i = 0; i < 4; i++) \
  _Pragma("unroll") for (int j = 0; j < 2; j++) \
    acc[(mh)*4 + i][(nh)*2 + j] = __builtin_amdgcn_mfma_f32_16x16x32_bf16( \
        af[i][ks], bfr[j][ks], acc[(mh)*4 + i][(nh)*2 + j], 0, 0, 0); \
  __builtin_amdgcn_s_setprio(0);
#define BAR1() __builtin_amdgcn_s_barrier(); \
  asm volatile("s_waitcnt lgkmcnt(0)" ::: "memory"); \
  __builtin_amdgcn_sched_barrier(0)

  f32x4 acc[8][4];
#pragma unroll
  for (int i = 0; i < 8; i++)
#pragma unroll
    for (int j = 0; j < 4; j++) acc[i][j] = (f32x4){0.f, 0.f, 0.f, 0.f};

  // prologue: stage K-tile 0 in wait-friendly order
  STG_A(0, 0, 0); STG_A(0, 0, 2);
  STG_B(0, 0, 0); STG_B(0, 0, 1); STG_B(0, 0, 2); STG_B(0, 0, 3);
  STG_A(0, 0, 1); STG_A(0, 0, 3);
  asm volatile("s_waitcnt vmcnt(2)" ::: "memory");  // A0,A2,B0-B3 landed
  __builtin_amdgcn_s_barrier();

  for (int tile = 0; tile < NT; ++tile) {
    const int cur = tile & 1, nxt = cur ^ 1;
    const bool hn = (tile + 1) < NT;
    bf16x8 af[4][2], bfr[2][2];
    // ---- phase 0: quad(mh=0, nh=0) ----
#pragma unroll
    for (int i = 0; i < 4; i++) { LDA(af[i][0], i, 0); LDA(af[i][1], i, 1); }
#pragma unroll
    for (int j = 0; j < 2; j++) { LDB(bfr[j][0], j, 0); LDB(bfr[j][1], j, 1); }
    if (hn) { STG_A(nxt, tile + 1, 0); STG_A(nxt, tile + 1, 2); }
    BAR1();
    MFMA16(0, 0);
    __builtin_amdgcn_s_barrier();
    // ---- phase 1: quad(0,1) — reuse af ----
#pragma unroll
    for (int j = 0; j < 2; j++) { LDB(bfr[j][0], 2 + j, 0); LDB(bfr[j][1], 2 + j, 1); }
    if (hn) { STG_B(nxt, tile + 1, 0); STG_B(nxt, tile + 1, 1); }
    BAR1();
    MFMA16(0, 1);
    if (hn) { asm volatile("s_waitcnt vmcnt(4)" ::: "memory"); }  // A-q1,q3 of cur landed
    else    { asm volatile("s_waitcnt vmcnt(0)" ::: "memory"); }
    __builtin_amdgcn_s_barrier();
    // ---- phase 2: quad(1,0) ----
#pragma unroll
    for (int i = 0; i < 4; i++) { LDA(af[i][0], 4 + i, 0); LDA(af[i][1], 4 + i, 1); }
#pragma unroll
    for (int j = 0; j < 2; j++) { LDB(bfr[j][0], j, 0); LDB(bfr[j][1], j, 1); }
    if (hn) { STG_B(nxt, tile + 1, 2); STG_B(nxt, tile + 1, 3); }
    BAR1();
    MFMA16(1, 0);
    __builtin_amdgcn_s_barrier();
    // ---- phase 3: quad(1,1) — reuse af ----
#pragma unroll
    for (int j = 0; j < 2; j++) { LDB(bfr[j][0], 2 + j, 0); LDB(bfr[j][1], 2 + j, 1); }
    if (hn) { STG_A(nxt, tile + 1, 1); STG_A(nxt, tile + 1, 3); }
    BAR1();
    MFMA16(1, 1);
    if (hn) { asm volatile("s_waitcnt vmcnt(2)" ::: "memory"); }  // next A0,A2,B0-B3 landed
    __builtin_amdgcn_s_barrier();
  }
#undef STG_A
#undef STG_B
#undef LDA
#undef LDB
#undef MFMA16
#undef BAR1

  // epilogue
#pragma unroll
  for (int mf = 0; mf < 8; mf++) {
    const int r = m0 + wr * 128 + mf * 16 + lb * 4;
#pragma unroll
    for (int nf = 0; nf < 4; nf++) {
      const int c = n0 + wc * 64 + nf * 16 + la;
      const float bv = bias[c];
#pragma unroll
      for (int rr = 0; rr < 4; rr++) {
        float v = acc[mf][nf][rr] + bv;
        if (RELU) v = fmaxf(v, 0.f);
        Cb[(size_t)(r + rr) * N + c] = f2bf(v);
      }
    }
  }
}

// ---------------- flash attention fwd (swapped QK^T, in-register P) ----------------
__global__ __launch_bounds__(256) void attn_fwd(const u16* __restrict__ Qg,
                                                const u16* __restrict__ Kg,
                                                const u16* __restrict__ Vg,
                                                u16* __restrict__ Og, int LDM) {
  constexpr int S = 2048, DH = 64, KB = 64, DMO = 1024;
  __shared__ u16 Ks[KB * DH];
  __shared__ u16 Vt[DH * KB];
  const int t = threadIdx.x, w = t >> 6, lane = t & 63;
  const int la = lane & 15, lb = lane >> 4;
  const int qb = blockIdx.x, h = blockIdx.y, b = blockIdx.z;
  const size_t base = ((size_t)b * S) * LDM + h * DH;
  const size_t obase = ((size_t)b * S) * DMO + h * DH;
  const int qrow0 = qb * 128 + w * 32;
  const int s0 = la + 32 * (lb & 1);
  const int s1 = s0 + 16;
  const int jsel = lb >> 1;

  bf16x8 qf[2][2];
#pragma unroll
  for (int rf = 0; rf < 2; rf++)
#pragma unroll
    for (int ks = 0; ks < 2; ks++)
      qf[rf][ks] = *(const bf16x8*)&Qg[base + (size_t)(qrow0 + rf * 16 + la) * LDM + ks * 32 + lb * 8];

  f32x4 accO[2][4];
  float m[2], l[2];
#pragma unroll
  for (int i = 0; i < 2; i++) {
    m[i] = -1e30f; l[i] = 0.f;
#pragma unroll
    for (int j = 0; j < 4; j++) accO[i][j] = (f32x4){0.f, 0.f, 0.f, 0.f};
  }

  const float SC = 0.125f * LOG2E;

  for (int kt = 0; kt < S; kt += KB) {
    __syncthreads();
#pragma unroll
    for (int i = 0; i < 2; i++) {
      const int s = i * 256 + t;
      const int row = s >> 3;
      const int colp = ((s & 7) ^ swz3(row)) << 3;
      gload_lds16(Kg + base + (size_t)(kt + row) * LDM + colp, &Ks[(i * 256 + w * 64) * 8]);
    }
#pragma unroll
    for (int i = 0; i < 2; i++) {
      const int s = i * 256 + t;
      const int row = s >> 3, col = (s & 7) * 8;
      bf16x8 vv = *(const bf16x8*)&Vg[base + (size_t)(kt + row) * LDM + col];
#pragma unroll
      for (int e = 0; e < 8; e++) {
        const int dr = col + e;
        Vt[dr * KB + (row ^ (swz3(dr) << 3))] = (u16)vv[e];
      }
    }
    __syncthreads();

    f32x4 st[4][2];
#pragma unroll
    for (int j = 0; j < 4; j++)
#pragma unroll
      for (int rf = 0; rf < 2; rf++) st[j][rf] = (f32x4){0.f, 0.f, 0.f, 0.f};
    __builtin_amdgcn_s_setprio(1);
#pragma unroll
    for (int ks = 0; ks < 2; ks++) {
      bf16x8 kf[4];
#pragma unroll
      for (int j = 0; j < 4; j++) {
        const int r = j * 16 + la;
        kf[j] = *(const bf16x8*)&Ks[r * DH + ((((ks << 2) + lb) ^ swz3(r)) << 3)];
      }
#pragma unroll
      for (int j = 0; j < 4; j++)
#pragma unroll
        for (int rf = 0; rf < 2; rf++)
          st[j][rf] = __builtin_amdgcn_mfma_f32_16x16x32_bf16(kf[j], qf[rf][ks], st[j][rf], 0, 0, 0);
    }
    __builtin_amdgcn_s_setprio(0);

    bf16x8 pf[2][2];
#pragma unroll
    for (int rf = 0; rf < 2; rf++) {
      float rm = st[0][rf][0];
#pragma unroll
      for (int j = 0; j < 4; j++)
#pragma unroll
        for (int rr = 0; rr < 4; rr++) rm = fmaxf(rm, st[j][rf][rr]);
      rm *= SC;
      if (__any(rm > m[rf])) {
        rm = fmaxf(rm, __shfl_xor(rm, 16, 64));
        rm = fmaxf(rm, __shfl_xor(rm, 32, 64));
        const float mN = fmaxf(m[rf], rm);
        const float al = exp2f(m[rf] - mN);
        m[rf] = mN;
        l[rf] *= al;
#pragma unroll
        for (int rr = 0; rr < 4; rr++) {
          const float alr = __shfl(al, (lb << 2) + rr, 64);
#pragma unroll
          for (int cf = 0; cf < 4; cf++) accO[rf][cf][rr] *= alr;
        }
      }
      uint32_t wl[4], wh[4];
#pragma unroll
      for (int j = 0; j < 4; j++) {
        float p0 = exp2f(st[j][rf][0] * SC - m[rf]);
        float p1 = exp2f(st[j][rf][1] * SC - m[rf]);
        float p2 = exp2f(st[j][rf][2] * SC - m[rf]);
        float p3 = exp2f(st[j][rf][3] * SC - m[rf]);
        l[rf] += (p0 + p1) + (p2 + p3);
        wl[j] = cvtpk(p0, p1);
        wh[j] = cvtpk(p2, p3);
      }
#pragma unroll
      for (int ks = 0; ks < 2; ks++) {
        const int j0 = 2 * ks, j1 = 2 * ks + 1;
        uint32_t a0 = __shfl(wl[j0], s0, 64), a1 = __shfl(wh[j0], s0, 64);
        uint32_t a2 = __shfl(wl[j0], s1, 64), a3 = __shfl(wh[j0], s1, 64);
        uint32_t b0 = __shfl(wl[j1], s0, 64), b1 = __shfl(wh[j1], s0, 64);
        uint32_t b2 = __shfl(wl[j1], s1, 64), b3 = __shfl(wh[j1], s1, 64);
        union { uint32_t u[4]; bf16x8 v; } pk;
        pk.u[0] = jsel ? b0 : a0;
        pk.u[1] = jsel ? b1 : a1;
        pk.u[2] = jsel ? b2 : a2;
        pk.u[3] = jsel ? b3 : a3;
        pf[rf][ks] = pk.v;
      }
    }

    __builtin_amdgcn_s_setprio(1);
#pragma unroll
    for (int ks = 0; ks < 2; ks++) {
      bf16x8 vf[4];
#pragma unroll
      for (int cf = 0; cf < 4; cf++) {
        const int dr = cf * 16 + la;
        vf[cf] = *(const bf16x8*)&Vt[dr * KB + ((((ks << 2) + lb) ^ swz3(dr)) << 3)];
      }
#pragma unroll
      for (int rf = 0; rf < 2; rf++)
#pragma unroll
        for (int cf = 0; cf < 4; cf++)
          accO[rf][cf] = __builtin_amdgcn_mfma_f32_16x16x32_bf16(pf[rf][ks], vf[cf], accO[rf][cf], 0, 0, 0);
    }
    __builtin_amdgcn_s_setprio(0);
  }

#pragma unroll
  for (int rf = 0; rf < 2; rf++) {
    float l2 = l[rf];
    l2 += __shfl_xor(l2, 16, 64);
    l2 += __shfl_xor(l2, 32, 64);
    const float inv = 1.0f / l2;
#pragma unroll
    for (int rr = 0; rr < 4; rr++) {
      const float invr = __shfl(inv, (lb << 2) + rr, 64);
      const int r = qrow0 + rf * 16 + lb * 4 + rr;
#pragma unroll
      for (int cf = 0; cf < 4; cf++)
        Og[obase + (size_t)r * DMO + cf * 16 + la] = f2bf_ru(accO[rf][cf][rr] * invr);
    }
  }
}

// ---------------- fused residual-add + LayerNorm (D=1024) ----------------
template <int AF32, int OUTF32>
__global__ __launch_bounds__(256) void add_ln(const void* __restrict__ Ap,
                                              const u16* __restrict__ Bb,
                                              const float* __restrict__ g,
                                              const float* __restrict__ be,
                                              void* __restrict__ Yp) {
  constexpr int D = 1024;
  const int row = blockIdx.x, t = threadIdx.x;
  f32x4 a;
  if (AF32) {
    a = ((const f32x4*)((const float*)Ap + (size_t)row * D))[t];
  } else {
    u16x4 av = ((const u16x4*)((const u16*)Ap + (size_t)row * D))[t];
#pragma unroll
    for (int i = 0; i < 4; i++) a[i] = bf2f(av[i]);
  }
  u16x4 bv16 = ((const u16x4*)(Bb + (size_t)row * D))[t];
  f32x4 x;
#pragma unroll
  for (int i = 0; i < 4; i++) x[i] = a[i] + bf2f(bv16[i]);
  float s1 = x[0] + x[1] + x[2] + x[3];
  float s2 = x[0] * x[0] + x[1] * x[1] + x[2] * x[2] + x[3] * x[3];
#pragma unroll
  for (int off = 32; off > 0; off >>= 1) {
    s1 += __shfl_down(s1, off, 64);
    s2 += __shfl_down(s2, off, 64);
  }
  __shared__ float sm[8];
  const int w = t >> 6, lane = t & 63;
  if (lane == 0) { sm[w] = s1; sm[4 + w] = s2; }
  __syncthreads();
  s1 = sm[0] + sm[1] + sm[2] + sm[3];
  s2 = sm[4] + sm[5] + sm[6] + sm[7];
  const float mean = s1 * (1.0f / D);
  const float var = s2 * (1.0f / D) - mean * mean;
  const float rstd = rsqrtf(var + 1e-5f);
  const f32x4 gv = ((const f32x4*)g)[t];
  const f32x4 bv = ((const f32x4*)be)[t];
  f32x4 y;
#pragma unroll
  for (int i = 0; i < 4; i++) y[i] = (x[i] - mean) * rstd * gv[i] + bv[i];
  if (OUTF32) {
    ((f32x4*)((float*)Yp + (size_t)row * D))[t] = y;
  } else {
    u16x4 o;
#pragma unroll
    for (int i = 0; i < 4; i++) o[i] = f2bf(y[i]);
    ((u16x4*)((u16*)Yp + (size_t)row * D))[t] = o;
  }
}

extern "C" void kernel_launch(void* const* d_in, const int* in_sizes, int n_in,
                              void* d_out, int out_size, void* d_ws, size_t ws_size,
                              hipStream_t stream) {
  const float* X   = (const float*)d_in[0];
  const float* Wq  = (const float*)d_in[1];
  const float* bq  = (const float*)d_in[2];
  const float* Wk  = (const float*)d_in[3];
  const float* bk  = (const float*)d_in[4];
  const float* Wv  = (const float*)d_in[5];
  const float* bv  = (const float*)d_in[6];
  const float* Wo  = (const float*)d_in[7];
  const float* bo  = (const float*)d_in[8];
  const float* g1  = (const float*)d_in[9];
  const float* be1 = (const float*)d_in[10];
  const float* W1  = (const float*)d_in[11];
  const float* b1  = (const float*)d_in[12];
  const float* W2  = (const float*)d_in[13];
  const float* b2  = (const float*)d_in[14];
  const float* g2  = (const float*)d_in[15];
  const float* be2 = (const float*)d_in[16];

  // ---- workspace plan (peak 120 MB, lifetime-aliased) ----
  const size_t MB = 1ull << 20;
  char* wsb = (char*)d_ws;
  u16*   WqkvT = (u16*)(wsb + 0 * MB);
  u16*   WoT   = (u16*)(wsb + 6 * MB);
  u16*   W1T   = (u16*)(wsb + 8 * MB);
  u16*   W2T   = (u16*)(wsb + 16 * MB);
  u16*   Xb    = (u16*)(wsb + 24 * MB);
  u16*   Ab    = (u16*)(wsb + 24 * MB);
  u16*   Fb    = (u16*)(wsb + 24 * MB);
  u16*   QKVb  = (u16*)(wsb + 40 * MB);
  u16*   Hb    = (u16*)(wsb + 40 * MB);
  float* bqkv  = (float*)(wsb + 88 * MB);
  u16*   Cx    = (u16*)(wsb + 88 * MB);
  u16*   Yb    = (u16*)(wsb + 104 * MB);
  (void)ws_size; (void)in_sizes; (void)n_in; (void)out_size;

  cast_bf16<<<2048, 256, 0, stream>>>(X, Xb, 8192 * 1024 / 8);
  concat3<<<12, 256, 0, stream>>>(bq, bk, bv, bqkv);
  transpose_cast<<<dim3(32, 32), 256, 0, stream>>>(Wq, WqkvT, 1024, 1024);
  transpose_cast<<<dim3(32, 32), 256, 0, stream>>>(Wk, WqkvT + 1024 * 1024, 1024, 1024);
  transpose_cast<<<dim3(32, 32), 256, 0, stream>>>(Wv, WqkvT + 2 * 1024 * 1024, 1024, 1024);
  transpose_cast<<<dim3(32, 32), 256, 0, stream>>>(Wo, WoT, 1024, 1024);
  transpose_cast<<<dim3(128, 32), 256, 0, stream>>>(W1, W1T, 1024, 4096);
  transpose_cast<<<dim3(32, 128), 256, 0, stream>>>(W2, W2T, 4096, 1024);

  // fused QKV projection: [8192,1024] @ [1024,3072]
  gemm8p<0><<<32 * 12, 512, 0, stream>>>(Xb, WqkvT, bqkv, QKVb, 8192, 3072, 1024, 12);

  attn_fwd<<<dim3(16, 16, 4), 256, 0, stream>>>(QKVb, QKVb + 1024, QKVb + 2048, Cx, 3072);

  gemm_bt<0><<<dim3(8, 64), 256, 0, stream>>>(Cx, WoT, bo, Ab, 8192, 1024, 1024);
  add_ln<1, 0><<<8192, 256, 0, stream>>>(X, Ab, g1, be1, Yb);
  gemm8p<1><<<32 * 16, 512, 0, stream>>>(Yb, W1T, b1, Hb, 8192, 4096, 1024, 16);
  gemm_bt<0><<<dim3(8, 64), 256, 0, stream>>>(Hb, W2T, b2, Fb, 8192, 1024, 4096);
  add_ln<0, 1><<<8192, 256, 0, stream>>>(Yb, Fb, g2, be2, d_out);
}

// Round 8
// 502.768 us; speedup vs baseline: 1.0772x; 1.0342x over previous
//
#include <hip/hip_runtime.h>
#include <stdint.h>

typedef unsigned short u16;
typedef short bf16x8 __attribute__((ext_vector_type(8)));
typedef float f32x4 __attribute__((ext_vector_type(4)));
typedef u16 u16x4 __attribute__((ext_vector_type(4)));
typedef u16 u16x8 __attribute__((ext_vector_type(8)));

#define LOG2E 1.4426950408889634f
#define QSCALE (0.125f * LOG2E)

__device__ __forceinline__ u16 f2bf(float f) {
  union { float f; uint32_t u; } x; x.f = f;
  uint32_t r = x.u + 0x7fffu + ((x.u >> 16) & 1u);
  return (u16)(r >> 16);
}
__device__ __forceinline__ u16 f2bf_ru(float f) {
  union { float f; uint32_t u; } x; x.f = f;
  return (u16)((x.u + 0x8000u) >> 16);
}
__device__ __forceinline__ float bf2f(u16 h) {
  union { uint32_t u; float f; } x; x.u = ((uint32_t)h) << 16;
  return x.f;
}
__device__ __forceinline__ uint32_t cvtpk(float lo, float hi) {
  uint32_t r;
  asm("v_cvt_pk_bf16_f32 %0, %1, %2" : "=v"(r) : "v"(lo), "v"(hi));
  return r;
}
// 16B-granule XOR swizzle (involution, low 3 bits of granule index)
__device__ __forceinline__ int swz3(int row) { return (row ^ (row >> 3)) & 7; }

__device__ __forceinline__ void gload_lds16(const void* g, void* lds) {
  __builtin_amdgcn_global_load_lds(
      (const __attribute__((address_space(1))) void*)g,
      (__attribute__((address_space(3))) void*)lds, 16, 0, 0);
}

// ---------------- cast f32 -> bf16 (8 elems/thread) ----------------
__global__ __launch_bounds__(256) void cast_bf16(const float* __restrict__ in,
                                                 u16* __restrict__ out, int n8) {
  int i = blockIdx.x * 256 + threadIdx.x;
  const int stride = gridDim.x * 256;
  for (; i < n8; i += stride) {
    const f32x4* p = (const f32x4*)in + (size_t)i * 2;
    f32x4 a = p[0], b = p[1];
    u16x8 o;
    o[0] = f2bf(a[0]); o[1] = f2bf(a[1]); o[2] = f2bf(a[2]); o[3] = f2bf(a[3]);
    o[4] = f2bf(b[0]); o[5] = f2bf(b[1]); o[6] = f2bf(b[2]); o[7] = f2bf(b[3]);
    ((u16x8*)out)[i] = o;
  }
}

// ---------------- concat 3 bias vectors; bq pre-scaled by QSCALE ----------------
__global__ __launch_bounds__(256) void concat3(const float* __restrict__ a,
                                               const float* __restrict__ b,
                                               const float* __restrict__ c,
                                               float* __restrict__ o) {
  int i = blockIdx.x * 256 + threadIdx.x;
  if (i < 3072)
    o[i] = i < 1024 ? a[i] * QSCALE : (i < 2048 ? b[i - 1024] : c[i - 2048]);
}

// ---------------- transpose + cast + scale: W[R][C] f32 -> WT[C][R] bf16 ----------------
__global__ __launch_bounds__(256) void transpose_cast(const float* __restrict__ in,
                                                      u16* __restrict__ out, int R, int C,
                                                      float scale) {
  __shared__ float tile[32][33];
  const int bc = blockIdx.x * 32, br = blockIdx.y * 32;
  const int tx = threadIdx.x & 31, ty = threadIdx.x >> 5;  // 32 x 8
#pragma unroll
  for (int i = 0; i < 32; i += 8)
    tile[ty + i][tx] = in[(size_t)(br + ty + i) * C + bc + tx];
  __syncthreads();
#pragma unroll
  for (int i = 0; i < 32; i += 8)
    out[(size_t)(bc + ty + i) * R + br + tx] = f2bf(tile[tx][ty + i] * scale);
}

// ---------------- V transpose: QKV V-part [s][dh] -> Vt_g[b*16+h][dh][S] ----------------
__global__ __launch_bounds__(256) void vtrans(const u16* __restrict__ QKV,
                                              u16* __restrict__ Vtg) {
  __shared__ u16 tl[64][65];
  const int t = threadIdx.x;
  const int sblk = blockIdx.x, h = blockIdx.y, b = blockIdx.z;
  const int s0 = sblk * 64;
  const size_t ibase = ((size_t)b * 2048) * 3072 + 2048 + h * 64;
#pragma unroll
  for (int i = 0; i < 2; i++) {
    const int idx = i * 256 + t;
    const int sl = idx >> 3, d0 = (idx & 7) * 8;
    bf16x8 v = *(const bf16x8*)&QKV[ibase + (size_t)(s0 + sl) * 3072 + d0];
#pragma unroll
    for (int e = 0; e < 8; e++) tl[d0 + e][sl] = (u16)v[e];
  }
  __syncthreads();
  const size_t ob = ((size_t)(b * 16 + h) * 64) * 2048;
#pragma unroll
  for (int i = 0; i < 2; i++) {
    const int idx = i * 256 + t;
    const int r = idx >> 3, c0 = (idx & 7) * 8;
    u16x8 o;
#pragma unroll
    for (int e = 0; e < 8; e++) o[e] = tl[r][c0 + e];
    *(u16x8*)&Vtg[ob + (size_t)r * 2048 + s0 + c0] = o;
  }
}

// ---------------- GEMM m97-structure (N=1024 shapes) ----------------
template <int RELU>
__global__ __launch_bounds__(256) void gemm_bt(const u16* __restrict__ A,
                                               const u16* __restrict__ BT,
                                               const float* __restrict__ bias,
                                               u16* __restrict__ Cb,
                                               int M, int N, int K) {
  constexpr int BM = 128, BN = 128, BK = 64;
  __shared__ u16 As[BM * BK];
  __shared__ u16 Bs[BN * BK];
  const int t = threadIdx.x;
  const int w = t >> 6, lane = t & 63;
  const int la = lane & 15, lb = lane >> 4;
  const int wr = w >> 1, wc = w & 1;
  const int m0 = blockIdx.y * BM, n0 = blockIdx.x * BN;

  f32x4 acc[4][4];
#pragma unroll
  for (int i = 0; i < 4; i++)
#pragma unroll
    for (int j = 0; j < 4; j++) acc[i][j] = (f32x4){0.f, 0.f, 0.f, 0.f};

  for (int kt = 0; kt < K; kt += BK) {
#pragma unroll
    for (int i = 0; i < 4; i++) {
      const int s = i * 256 + t;
      const int row = s >> 3, col = (s & 7) * 8;
      gload_lds16(A + (size_t)(m0 + row) * K + kt + col, &As[(i * 256 + w * 64) * 8]);
      gload_lds16(BT + (size_t)(n0 + row) * K + kt + col, &Bs[(i * 256 + w * 64) * 8]);
    }
    __syncthreads();
#pragma unroll
    for (int ks = 0; ks < 2; ks++) {
      bf16x8 af[4], bfr[4];
#pragma unroll
      for (int i = 0; i < 4; i++)
        af[i] = *(const bf16x8*)&As[(wr * 64 + i * 16 + la) * BK + ks * 32 + lb * 8];
#pragma unroll
      for (int j = 0; j < 4; j++)
        bfr[j] = *(const bf16x8*)&Bs[(wc * 64 + j * 16 + la) * BK + ks * 32 + lb * 8];
#pragma unroll
      for (int i = 0; i < 4; i++)
#pragma unroll
        for (int j = 0; j < 4; j++)
          acc[i][j] = __builtin_amdgcn_mfma_f32_16x16x32_bf16(af[i], bfr[j], acc[i][j], 0, 0, 0);
    }
    __syncthreads();
  }
#pragma unroll
  for (int i = 0; i < 4; i++) {
    const int r = m0 + wr * 64 + i * 16 + lb * 4;
#pragma unroll
    for (int j = 0; j < 4; j++) {
      const int c = n0 + wc * 64 + j * 16 + la;
      const float bv = bias[c];
#pragma unroll
      for (int rr = 0; rr < 4; rr++) {
        float v = acc[i][j][rr] + bv;
        if (RELU) v = fmaxf(v, 0.f);
        Cb[(size_t)(r + rr) * N + c] = f2bf(v);
      }
    }
  }
}

// ---------------- GEMM 256x256, 4-phase interleave + counted vmcnt ----------------
template <int RELU>
__global__ __launch_bounds__(512, 2) void gemm8p(const u16* __restrict__ A,
                                                 const u16* __restrict__ BT,
                                                 const float* __restrict__ bias,
                                                 u16* __restrict__ Cb,
                                                 int M, int N, int K, int nbx) {
  __shared__ u16 As[2][256 * 64];
  __shared__ u16 Bs[2][256 * 64];
  const int t = threadIdx.x;
  const int w = t >> 6, lane = t & 63;
  const int la = lane & 15, lb = lane >> 4;
  const int wr = w >> 2, wc = w & 3;
  int bid = (int)blockIdx.x;
  const int cpx = (int)gridDim.x >> 3;
  bid = (bid & 7) * cpx + (bid >> 3);
  const int m0 = (bid / nbx) * 256, n0 = (bid % nbx) * 256;
  const int NT = K >> 6;
  const int row64 = t >> 3;
  const int colp = ((t & 7) ^ swz3(row64)) << 3;

#define STG_A(buf, tile, q) \
  gload_lds16(A + (size_t)(m0 + (q)*64 + row64) * K + ((tile) << 6) + colp, \
              &As[buf][(q)*4096 + w * 512])
#define STG_B(buf, tile, q) \
  gload_lds16(BT + (size_t)(n0 + (q)*64 + row64) * K + ((tile) << 6) + colp, \
              &Bs[buf][(q)*4096 + w * 512])
#define LDA(dst, mf, ks) { const int r_ = wr * 128 + (mf)*16 + la; \
  dst = *(const bf16x8*)&As[cur][r_ * 64 + (((((ks) << 2) + lb) ^ swz3(r_)) << 3)]; }
#define LDB(dst, nf, ks) { const int r_ = wc * 64 + (nf)*16 + la; \
  dst = *(const bf16x8*)&Bs[cur][r_ * 64 + (((((ks) << 2) + lb) ^ swz3(r_)) << 3)]; }
#define MFMA16(mh, nh) \
  __builtin_amdgcn_s_setprio(1); \
  _Pragma("unroll") for (int ks = 0; ks < 2; ks++) \
  _Pragma("unroll") for (int i = 0; i < 4; i++) \
  _Pragma("unroll") for (int j = 0; j < 2; j++) \
    acc[(mh)*4 + i][(nh)*2 + j] = __builtin_amdgcn_mfma_f32_16x16x32_bf16( \
        af[i][ks], bfr[j][ks], acc[(mh)*4 + i][(nh)*2 + j], 0, 0, 0); \
  __builtin_amdgcn_s_setprio(0);
#define BAR1() __builtin_amdgcn_s_barrier(); \
  asm volatile("s_waitcnt lgkmcnt(0)" ::: "memory"); \
  __builtin_amdgcn_sched_barrier(0)

  f32x4 acc[8][4];
#pragma unroll
  for (int i = 0; i < 8; i++)
#pragma unroll
    for (int j = 0; j < 4; j++) acc[i][j] = (f32x4){0.f, 0.f, 0.f, 0.f};

  STG_A(0, 0, 0); STG_A(0, 0, 2);
  STG_B(0, 0, 0); STG_B(0, 0, 1); STG_B(0, 0, 2); STG_B(0, 0, 3);
  STG_A(0, 0, 1); STG_A(0, 0, 3);
  asm volatile("s_waitcnt vmcnt(2)" ::: "memory");
  __builtin_amdgcn_s_barrier();

  for (int tile = 0; tile < NT; ++tile) {
    const int cur = tile & 1, nxt = cur ^ 1;
    const bool hn = (tile + 1) < NT;
    bf16x8 af[4][2], bfr[2][2];
#pragma unroll
    for (int i = 0; i < 4; i++) { LDA(af[i][0], i, 0); LDA(af[i][1], i, 1); }
#pragma unroll
    for (int j = 0; j < 2; j++) { LDB(bfr[j][0], j, 0); LDB(bfr[j][1], j, 1); }
    if (hn) { STG_A(nxt, tile + 1, 0); STG_A(nxt, tile + 1, 2); }
    BAR1();
    MFMA16(0, 0);
    __builtin_amdgcn_s_barrier();
#pragma unroll
    for (int j = 0; j < 2; j++) { LDB(bfr[j][0], 2 + j, 0); LDB(bfr[j][1], 2 + j, 1); }
    if (hn) { STG_B(nxt, tile + 1, 0); STG_B(nxt, tile + 1, 1); }
    BAR1();
    MFMA16(0, 1);
    if (hn) { asm volatile("s_waitcnt vmcnt(4)" ::: "memory"); }
    else    { asm volatile("s_waitcnt vmcnt(0)" ::: "memory"); }
    __builtin_amdgcn_s_barrier();
#pragma unroll
    for (int i = 0; i < 4; i++) { LDA(af[i][0], 4 + i, 0); LDA(af[i][1], 4 + i, 1); }
#pragma unroll
    for (int j = 0; j < 2; j++) { LDB(bfr[j][0], j, 0); LDB(bfr[j][1], j, 1); }
    if (hn) { STG_B(nxt, tile + 1, 2); STG_B(nxt, tile + 1, 3); }
    BAR1();
    MFMA16(1, 0);
    __builtin_amdgcn_s_barrier();
#pragma unroll
    for (int j = 0; j < 2; j++) { LDB(bfr[j][0], 2 + j, 0); LDB(bfr[j][1], 2 + j, 1); }
    if (hn) { STG_A(nxt, tile + 1, 1); STG_A(nxt, tile + 1, 3); }
    BAR1();
    MFMA16(1, 1);
    if (hn) { asm volatile("s_waitcnt vmcnt(2)" ::: "memory"); }
    __builtin_amdgcn_s_barrier();
  }
#undef STG_A
#undef STG_B
#undef LDA
#undef LDB
#undef MFMA16
#undef BAR1

#pragma unroll
  for (int mf = 0; mf < 8; mf++) {
    const int r = m0 + wr * 128 + mf * 16 + lb * 4;
#pragma unroll
    for (int nf = 0; nf < 4; nf++) {
      const int c = n0 + wc * 64 + nf * 16 + la;
      const float bv = bias[c];
#pragma unroll
      for (int rr = 0; rr < 4; rr++) {
        float v = acc[mf][nf][rr] + bv;
        if (RELU) v = fmaxf(v, 0.f);
        Cb[(size_t)(r + rr) * N + c] = f2bf(v);
      }
    }
  }
}

// ---------------- flash attention fwd ----------------
// Swapped QK^T + in-register P; KV double-buffered (KVBLK=128) with prefetch;
// V pre-transposed globally (Vtg[b*16+h][dh][S]); Q pre-scaled by QSCALE.
__global__ __launch_bounds__(256) void attn_fwd(const u16* __restrict__ Qg,
                                                const u16* __restrict__ Kg,
                                                const u16* __restrict__ Vtg,
                                                u16* __restrict__ Og, int LDM) {
  constexpr int S = 2048, DMO = 1024;
  __shared__ u16 Ks[2][128 * 64];  // [kv][dh], swizzled granules
  __shared__ u16 Vt[2][64 * 128];  // [dh][kv], swizzled granules
  const int t = threadIdx.x, w = t >> 6, lane = t & 63;
  const int la = lane & 15, lb = lane >> 4;
  const int qb = blockIdx.x, h = blockIdx.y, b = blockIdx.z;
  const size_t base = ((size_t)b * S) * LDM + h * 64;
  const size_t vbase = ((size_t)(b * 16 + h) * 64) * 2048;
  const size_t obase = ((size_t)b * S) * DMO + h * 64;
  const int qrow0 = qb * 128 + w * 32;
  const int sl0 = la + 32 * (lb & 1), sl1 = sl0 + 16;
  const int jsel = lb >> 1;

#define ATT_STAGE(buf, kt_) { \
  _Pragma("unroll") for (int i = 0; i < 4; i++) { \
    const int s = i * 256 + t; const int r = s >> 3; const int cg = s & 7; \
    gload_lds16(Kg + base + (size_t)((kt_) + r) * LDM + ((cg ^ swz3(r)) << 3), \
                &Ks[buf][s * 8]); } \
  _Pragma("unroll") for (int i = 0; i < 4; i++) { \
    const int s = i * 256 + t; const int r = s >> 4; const int cg = s & 15; \
    gload_lds16(Vtg + vbase + (size_t)r * 2048 + (kt_) + ((cg ^ swz3(r)) << 3), \
                &Vt[buf][s * 8]); } }

  bf16x8 qf[2][2];
#pragma unroll
  for (int rf = 0; rf < 2; rf++)
#pragma unroll
    for (int ks = 0; ks < 2; ks++)
      qf[rf][ks] = *(const bf16x8*)&Qg[base + (size_t)(qrow0 + rf * 16 + la) * LDM + ks * 32 + lb * 8];

  f32x4 accO[2][4];
  float m[2], l[2];  // per-lane row state for q = qrow0 + 16rf + la
#pragma unroll
  for (int i = 0; i < 2; i++) {
    m[i] = -1e30f; l[i] = 0.f;
#pragma unroll
    for (int j = 0; j < 4; j++) accO[i][j] = (f32x4){0.f, 0.f, 0.f, 0.f};
  }

  ATT_STAGE(0, 0);
  asm volatile("s_waitcnt vmcnt(0)" ::: "memory");
  __builtin_amdgcn_s_barrier();

  for (int kt2 = 0; kt2 < S / 128; ++kt2) {
    const int cur = kt2 & 1;
    if (kt2 + 1 < S / 128) ATT_STAGE(cur ^ 1, (kt2 + 1) * 128);

#pragma unroll
    for (int sub = 0; sub < 2; ++sub) {
      // S^T = K @ Q^T : lane holds q=la, kv=16j+4lb+rr (log2 domain, Q pre-scaled)
      f32x4 st[4][2];
#pragma unroll
      for (int j = 0; j < 4; j++)
#pragma unroll
        for (int rf = 0; rf < 2; rf++) st[j][rf] = (f32x4){0.f, 0.f, 0.f, 0.f};
      __builtin_amdgcn_s_setprio(1);
#pragma unroll
      for (int ks = 0; ks < 2; ks++) {
        bf16x8 kf[4];
#pragma unroll
        for (int j = 0; j < 4; j++) {
          const int r = sub * 64 + j * 16 + la;
          kf[j] = *(const bf16x8*)&Ks[cur][r * 64 + ((((ks << 2) + lb) ^ swz3(r)) << 3)];
        }
#pragma unroll
        for (int j = 0; j < 4; j++)
#pragma unroll
          for (int rf = 0; rf < 2; rf++)
            st[j][rf] = __builtin_amdgcn_mfma_f32_16x16x32_bf16(kf[j], qf[rf][ks], st[j][rf], 0, 0, 0);
      }
      __builtin_amdgcn_s_setprio(0);

      bf16x8 pf[2][2];
#pragma unroll
      for (int rf = 0; rf < 2; rf++) {
        float rm = st[0][rf][0];
#pragma unroll
        for (int j = 0; j < 4; j++)
#pragma unroll
          for (int rr = 0; rr < 4; rr++) rm = fmaxf(rm, st[j][rf][rr]);
        if (__any(rm > m[rf] + 8.0f)) {  // defer-max, THR=8 (log2 units)
          rm = fmaxf(rm, __shfl_xor(rm, 16, 64));
          rm = fmaxf(rm, __shfl_xor(rm, 32, 64));
          const float mN = fmaxf(m[rf], rm);
          const float al = exp2f(m[rf] - mN);
          m[rf] = mN;
          l[rf] *= al;
#pragma unroll
          for (int rr = 0; rr < 4; rr++) {
            const float alr = __shfl(al, (lb << 2) + rr, 64);
#pragma unroll
            for (int cf = 0; cf < 4; cf++) accO[rf][cf][rr] *= alr;
          }
        }
        uint32_t wl[4], wh[4];
#pragma unroll
        for (int j = 0; j < 4; j++) {
          float p0 = exp2f(st[j][rf][0] - m[rf]);
          float p1 = exp2f(st[j][rf][1] - m[rf]);
          float p2 = exp2f(st[j][rf][2] - m[rf]);
          float p3 = exp2f(st[j][rf][3] - m[rf]);
          l[rf] += (p0 + p1) + (p2 + p3);
          wl[j] = cvtpk(p0, p1);
          wh[j] = cvtpk(p2, p3);
        }
        // kv-exchange to A-operand layout
#pragma unroll
        for (int ks = 0; ks < 2; ks++) {
          const int j0 = 2 * ks, j1 = 2 * ks + 1;
          uint32_t a0 = __shfl(wl[j0], sl0, 64), a1 = __shfl(wh[j0], sl0, 64);
          uint32_t a2 = __shfl(wl[j0], sl1, 64), a3 = __shfl(wh[j0], sl1, 64);
          uint32_t b0 = __shfl(wl[j1], sl0, 64), b1 = __shfl(wh[j1], sl0, 64);
          uint32_t b2 = __shfl(wl[j1], sl1, 64), b3 = __shfl(wh[j1], sl1, 64);
          union { uint32_t u[4]; bf16x8 v; } pk;
          pk.u[0] = jsel ? b0 : a0;
          pk.u[1] = jsel ? b1 : a1;
          pk.u[2] = jsel ? b2 : a2;
          pk.u[3] = jsel ? b3 : a3;
          pf[rf][ks] = pk.v;
        }
      }

      // O += P @ V
      __builtin_amdgcn_s_setprio(1);
#pragma unroll
      for (int ks = 0; ks < 2; ks++) {
        bf16x8 vf[4];
#pragma unroll
        for (int cf = 0; cf < 4; cf++) {
          const int dr = cf * 16 + la;
          const int g = sub * 8 + ks * 4 + lb;
          vf[cf] = *(const bf16x8*)&Vt[cur][dr * 128 + ((g ^ swz3(dr)) << 3)];
        }
#pragma unroll
        for (int rf = 0; rf < 2; rf++)
#pragma unroll
          for (int cf = 0; cf < 4; cf++)
            accO[rf][cf] = __builtin_amdgcn_mfma_f32_16x16x32_bf16(pf[rf][ks], vf[cf], accO[rf][cf], 0, 0, 0);
      }
      __builtin_amdgcn_s_setprio(0);
    }

    asm volatile("s_waitcnt vmcnt(0)" ::: "memory");  // prefetch landed (hidden by compute)
    __builtin_amdgcn_s_barrier();
  }
#undef ATT_STAGE

  // epilogue: reduce l across lb lanes, normalize, write
#pragma unroll
  for (int rf = 0; rf < 2; rf++) {
    float l2 = l[rf];
    l2 += __shfl_xor(l2, 16, 64);
    l2 += __shfl_xor(l2, 32, 64);
    const float inv = 1.0f / l2;
#pragma unroll
    for (int rr = 0; rr < 4; rr++) {
      const float invr = __shfl(inv, (lb << 2) + rr, 64);
      const int r = qrow0 + rf * 16 + lb * 4 + rr;
#pragma unroll
      for (int cf = 0; cf < 4; cf++)
        Og[obase + (size_t)r * DMO + cf * 16 + la] = f2bf_ru(accO[rf][cf][rr] * invr);
    }
  }
}

// ---------------- fused residual-add + LayerNorm (D=1024) ----------------
template <int AF32, int OUTF32>
__global__ __launch_bounds__(256) void add_ln(const void* __restrict__ Ap,
                                              const u16* __restrict__ Bb,
                                              const float* __restrict__ g,
                                              const float* __restrict__ be,
                                              void* __restrict__ Yp) {
  constexpr int D = 1024;
  const int row = blockIdx.x, t = threadIdx.x;
  f32x4 a;
  if (AF32) {
    a = ((const f32x4*)((const float*)Ap + (size_t)row * D))[t];
  } else {
    u16x4 av = ((const u16x4*)((const u16*)Ap + (size_t)row * D))[t];
#pragma unroll
    for (int i = 0; i < 4; i++) a[i] = bf2f(av[i]);
  }
  u16x4 bv16 = ((const u16x4*)(Bb + (size_t)row * D))[t];
  f32x4 x;
#pragma unroll
  for (int i = 0; i < 4; i++) x[i] = a[i] + bf2f(bv16[i]);
  float s1 = x[0] + x[1] + x[2] + x[3];
  float s2 = x[0] * x[0] + x[1] * x[1] + x[2] * x[2] + x[3] * x[3];
#pragma unroll
  for (int off = 32; off > 0; off >>= 1) {
    s1 += __shfl_down(s1, off, 64);
    s2 += __shfl_down(s2, off, 64);
  }
  __shared__ float sm[8];
  const int w = t >> 6, lane = t & 63;
  if (lane == 0) { sm[w] = s1; sm[4 + w] = s2; }
  __syncthreads();
  s1 = sm[0] + sm[1] + sm[2] + sm[3];
  s2 = sm[4] + sm[5] + sm[6] + sm[7];
  const float mean = s1 * (1.0f / D);
  const float var = s2 * (1.0f / D) - mean * mean;
  const float rstd = rsqrtf(var + 1e-5f);
  const f32x4 gv = ((const f32x4*)g)[t];
  const f32x4 bv = ((const f32x4*)be)[t];
  f32x4 y;
#pragma unroll
  for (int i = 0; i < 4; i++) y[i] = (x[i] - mean) * rstd * gv[i] + bv[i];
  if (OUTF32) {
    ((f32x4*)((float*)Yp + (size_t)row * D))[t] = y;
  } else {
    u16x4 o;
#pragma unroll
    for (int i = 0; i < 4; i++) o[i] = f2bf(y[i]);
    ((u16x4*)((u16*)Yp + (size_t)row * D))[t] = o;
  }
}

extern "C" void kernel_launch(void* const* d_in, const int* in_sizes, int n_in,
                              void* d_out, int out_size, void* d_ws, size_t ws_size,
                              hipStream_t stream) {
  const float* X   = (const float*)d_in[0];
  const float* Wq  = (const float*)d_in[1];
  const float* bq  = (const float*)d_in[2];
  const float* Wk  = (const float*)d_in[3];
  const float* bk  = (const float*)d_in[4];
  const float* Wv  = (const float*)d_in[5];
  const float* bv  = (const float*)d_in[6];
  const float* Wo  = (const float*)d_in[7];
  const float* bo  = (const float*)d_in[8];
  const float* g1  = (const float*)d_in[9];
  const float* be1 = (const float*)d_in[10];
  const float* W1  = (const float*)d_in[11];
  const float* b1  = (const float*)d_in[12];
  const float* W2  = (const float*)d_in[13];
  const float* b2  = (const float*)d_in[14];
  const float* g2  = (const float*)d_in[15];
  const float* be2 = (const float*)d_in[16];

  // ---- workspace plan (peak 120 MB, lifetime-aliased) ----
  // [0,6)   WqkvT   [6,8) WoT   [8,16) W1T   [16,24) W2T
  // [24,40) Xb -> Ab -> Fb
  // [40,88) QKVb -> Hb [40,104)
  // [88,104) bqkv then Cx
  // [104,120) Vt_g (vtrans->attn) -> Yb (LN1->LN2)   [both 16 MiB exactly]
  const size_t MB = 1ull << 20;
  char* wsb = (char*)d_ws;
  u16*   WqkvT = (u16*)(wsb + 0 * MB);
  u16*   WoT   = (u16*)(wsb + 6 * MB);
  u16*   W1T   = (u16*)(wsb + 8 * MB);
  u16*   W2T   = (u16*)(wsb + 16 * MB);
  u16*   Xb    = (u16*)(wsb + 24 * MB);
  u16*   Ab    = (u16*)(wsb + 24 * MB);
  u16*   Fb    = (u16*)(wsb + 24 * MB);
  u16*   QKVb  = (u16*)(wsb + 40 * MB);
  u16*   Hb    = (u16*)(wsb + 40 * MB);
  float* bqkv  = (float*)(wsb + 88 * MB);
  u16*   Cx    = (u16*)(wsb + 88 * MB);
  u16*   Vt_g  = (u16*)(wsb + 104 * MB);
  u16*   Yb    = (u16*)(wsb + 104 * MB);
  (void)ws_size; (void)in_sizes; (void)n_in; (void)out_size;

  cast_bf16<<<2048, 256, 0, stream>>>(X, Xb, 8192 * 1024 / 8);
  concat3<<<12, 256, 0, stream>>>(bq, bk, bv, bqkv);
  transpose_cast<<<dim3(32, 32), 256, 0, stream>>>(Wq, WqkvT, 1024, 1024, QSCALE);
  transpose_cast<<<dim3(32, 32), 256, 0, stream>>>(Wk, WqkvT + 1024 * 1024, 1024, 1024, 1.0f);
  transpose_cast<<<dim3(32, 32), 256, 0, stream>>>(Wv, WqkvT + 2 * 1024 * 1024, 1024, 1024, 1.0f);
  transpose_cast<<<dim3(32, 32), 256, 0, stream>>>(Wo, WoT, 1024, 1024, 1.0f);
  transpose_cast<<<dim3(128, 32), 256, 0, stream>>>(W1, W1T, 1024, 4096, 1.0f);
  transpose_cast<<<dim3(32, 128), 256, 0, stream>>>(W2, W2T, 4096, 1024, 1.0f);

  // fused QKV projection (Q pre-scaled): [8192,1024] @ [1024,3072]
  gemm8p<0><<<32 * 12, 512, 0, stream>>>(Xb, WqkvT, bqkv, QKVb, 8192, 3072, 1024, 12);

  vtrans<<<dim3(32, 16, 4), 256, 0, stream>>>(QKVb, Vt_g);
  attn_fwd<<<dim3(16, 16, 4), 256, 0, stream>>>(QKVb, QKVb + 1024, Vt_g, Cx, 3072);

  gemm_bt<0><<<dim3(8, 64), 256, 0, stream>>>(Cx, WoT, bo, Ab, 8192, 1024, 1024);
  add_ln<1, 0><<<8192, 256, 0, stream>>>(X, Ab, g1, be1, Yb);
  gemm8p<1><<<32 * 16, 512, 0, stream>>>(Yb, W1T, b1, Hb, 8192, 4096, 1024, 16);
  gemm_bt<0><<<dim3(8, 64), 256, 0, stream>>>(Hb, W2T, b2, Fb, 8192, 1024, 4096);
  add_ln<0, 1><<<8192, 256, 0, stream>>>(Yb, Fb, g2, be2, d_out);
}